// Round 4
// baseline (3203.424 us; speedup 1.0000x reference)
//
#include <hip/hip_runtime.h>

#define NV 500000
#define KOFF 27
#define CIN_ 32
#define COUT_ 64
#define EPS_ 1e-5f

typedef __attribute__((ext_vector_type(8))) _Float16 half8;
typedef __attribute__((ext_vector_type(4))) float floatx4;

// ws layout: y1h NV*64 f16 | xh NV*32 f16 | wT1 27*64*32 f16 | wT2 27*64*64 f16 | st 768 f32

__global__ void zero_stats_kernel(float* __restrict__ s) {
  if (threadIdx.x < 384) s[threadIdx.x] = 0.f;
}

__global__ __launch_bounds__(256) void cast_x_kernel(
    const float* __restrict__ x, _Float16* __restrict__ xh) {
  size_t q = (size_t)blockIdx.x * 256 + threadIdx.x;
  if (q >= (size_t)NV * CIN_ / 8) return;
  const float4* xp = (const float4*)x;
  float4 a = xp[2 * q], b = xp[2 * q + 1];
  half8 h;
  h[0] = (_Float16)a.x; h[1] = (_Float16)a.y; h[2] = (_Float16)a.z; h[3] = (_Float16)a.w;
  h[4] = (_Float16)b.x; h[5] = (_Float16)b.y; h[6] = (_Float16)b.z; h[7] = (_Float16)b.w;
  ((half8*)xh)[q] = h;
}

// wT[k][co][ci] = (f16) w[k][ci][co]
__global__ void wtrans_kernel(const float* __restrict__ w,
                              _Float16* __restrict__ wT, int CI) {
  int t = blockIdx.x * 256 + threadIdx.x;
  int total = KOFF * CI * COUT_;
  if (t >= total) return;
  int k = t / (CI * COUT_);
  int r = t % (CI * COUT_);
  int co = r / CI;
  int ci = r % CI;
  wT[t] = (_Float16)w[(k * CI + ci) * COUT_ + co];
}

// ---- conv v8: 1024-thr blocks, 16 waves, deep per-wave gather pipeline ----
// Round-3 lesson: every pipe <15% busy; gather throughput tracks in-flight
// gather instructions per CU (v3: 192 -> 3.2 TB/s, v6: ~100 -> 2.5 TB/s).
// v8 maximizes in-flight within the proven (1024,4) 128-reg cap:
//   conv1 (CI=32): KPC=27 single phase (wT1 fully LDS-resident, 138KB),
//                  ring D=8 -> 128 in-flight insts, ONE stage barrier total.
//   conv2 (CI=64): 3 phases of KPC=9 (82.9KB LDS), ring D=7 -> 224 in-flight,
//                  3 drains (vs v6's 9). Phase indices all preloaded.

template<int CI, int PAD>
__device__ __forceinline__ void stageB_v8(const _Float16* __restrict__ wT,
                                          _Float16* __restrict__ lds,
                                          int k0, int kp, int tid) {
  __syncthreads();  // all waves done reading previous phase's LDS
  const int segs = CI / 8;
  const int chunks = kp * COUT_ * segs;
  for (int idx = tid; idx < chunks; idx += 1024) {
    int row = idx / segs;
    int s = idx - row * segs;
    half8 v = *(const half8*)(wT + ((size_t)k0 * COUT_ + row) * CI + s * 8);
    *(half8*)(lds + (size_t)row * (CI + PAD) + s * 8) = v;
  }
  __syncthreads();
}

template<int CI, int PAD, int KPC, int D>
__device__ __forceinline__ void run_phase_v8(
    const half8* __restrict__ fp, const int* __restrict__ nbr,
    const _Float16* __restrict__ lds, int k0,
    int v0, int m, int quad, floatx4 acc[4]) {
  constexpr int SEG = CI / 32;
  constexpr int ROWH8 = CI / 8;

  // preload ALL phase indices first (parallel, vmcnt drains in order)
  int j0[KPC];
#pragma unroll
  for (int k = 0; k < KPC; ++k) j0[k] = nbr[(k0 + k) * NV + v0] * ROWH8;

  // deep ring: D gather slots in flight per wave
  half8 ring[D][SEG];
#pragma unroll
  for (int p = 0; p < D; ++p)
#pragma unroll
    for (int s = 0; s < SEG; ++s)
      ring[p][s] = fp[(size_t)j0[p] + s * 4 + quad];

#pragma unroll
  for (int k = 0; k < KPC; ++k) {
    const _Float16* bk = lds + (size_t)k * COUT_ * (CI + PAD);
#pragma unroll
    for (int s = 0; s < SEG; ++s)
#pragma unroll
      for (int nf = 0; nf < 4; ++nf) {
        half8 bf = *(const half8*)(bk + (nf * 16 + m) * (CI + PAD) + s * 32 + quad * 8);
        acc[nf] = __builtin_amdgcn_mfma_f32_16x16x32_f16(ring[k % D][s], bf, acc[nf], 0, 0, 0);
      }
    if (k + D < KPC) {
#pragma unroll
      for (int s = 0; s < SEG; ++s)
        ring[k % D][s] = fp[(size_t)j0[k + D] + s * 4 + quad];
    }
  }
}

template<int CI, bool WF16>
__global__ __launch_bounds__(1024, 4) void conv_mfma_v8(
    const _Float16* __restrict__ feats, const int* __restrict__ nbr,
    const _Float16* __restrict__ wT, float* __restrict__ outF,
    _Float16* __restrict__ outH, float* __restrict__ stOut) {
  // conv1: full wT1 resident: 27*64*40*2 = 138.2KB. conv2: 9*64*72*2 = 82.9KB.
  constexpr int PAD = 8;
  constexpr int LDSH = (CI == 64) ? 9 * 64 * (64 + PAD) : 27 * 64 * (32 + PAD);
  __shared__ __align__(16) _Float16 ldsB[LDSH];
  __shared__ float bs[128];  // block-level stats reduce (sum | sumsq)

  int tid = threadIdx.x;
  int wave = tid >> 6, lane = tid & 63;
  int m = lane & 15, quad = lane >> 4;
  int vbase = (blockIdx.x * 16 + wave) * 16;  // 16 voxels per wave
  int v0 = vbase + m;
  v0 = v0 < NV ? v0 : NV - 1;
  const half8* fp = (const half8*)feats;

  if (tid < 128) bs[tid] = 0.f;  // ordered by stageB's first __syncthreads

  floatx4 acc[4];
#pragma unroll
  for (int nf = 0; nf < 4; ++nf) acc[nf] = (floatx4){0.f, 0.f, 0.f, 0.f};

  if constexpr (CI == 64) {
    stageB_v8<CI, PAD>(wT, ldsB, 0, 9, tid);
    run_phase_v8<CI, PAD, 9, 7>(fp, nbr, ldsB, 0, v0, m, quad, acc);
    stageB_v8<CI, PAD>(wT, ldsB, 9, 9, tid);
    run_phase_v8<CI, PAD, 9, 7>(fp, nbr, ldsB, 9, v0, m, quad, acc);
    stageB_v8<CI, PAD>(wT, ldsB, 18, 9, tid);
    run_phase_v8<CI, PAD, 9, 7>(fp, nbr, ldsB, 18, v0, m, quad, acc);
  } else {
    stageB_v8<CI, PAD>(wT, ldsB, 0, 27, tid);   // single stage, whole wT1
    run_phase_v8<CI, PAD, 27, 8>(fp, nbr, ldsB, 0, v0, m, quad, acc);
  }

  // epilogue: store + fused BN stats (sum / sumsq per channel)
  float s4[4], q4[4];
#pragma unroll
  for (int nf = 0; nf < 4; ++nf) {
    float s = 0.f, q = 0.f;
#pragma unroll
    for (int r = 0; r < 4; ++r) {
      int row = vbase + quad * 4 + r;
      if (row < NV) {
        float v = acc[nf][r];
        size_t o = (size_t)row * COUT_ + nf * 16 + m;
        if constexpr (WF16) outH[o] = (_Float16)v;
        else outF[o] = v;
        s += v;
        q = fmaf(v, v, q);
      }
    }
    s4[nf] = s; q4[nf] = q;
  }
  // reduce over the 4 quads: lanes m, m+16, m+32, m+48 hold channel nf*16+m
#pragma unroll
  for (int nf = 0; nf < 4; ++nf) {
    s4[nf] += __shfl_xor(s4[nf], 16); s4[nf] += __shfl_xor(s4[nf], 32);
    q4[nf] += __shfl_xor(q4[nf], 16); q4[nf] += __shfl_xor(q4[nf], 32);
  }
  if (quad == 0) {
#pragma unroll
    for (int nf = 0; nf < 4; ++nf) {
      atomicAdd(&bs[nf * 16 + m], s4[nf]);
      atomicAdd(&bs[64 + nf * 16 + m], q4[nf]);
    }
  }
  __syncthreads();
  if (tid < 128) atomicAdd(&stOut[tid], bs[tid]);
}

// ---- ident stats / BN finalize / epilogue kernels ----

__global__ __launch_bounds__(256) void ident_stats_kernel(
    const float* __restrict__ x, const float* __restrict__ wid,
    float* __restrict__ sums) {
  int lane = threadIdx.x & 63;
  int wv = blockIdx.x * 4 + (threadIdx.x >> 6);
  int nw = gridDim.x * 4;
  float wcol[CIN_];
#pragma unroll
  for (int ci = 0; ci < CIN_; ++ci) wcol[ci] = wid[ci * COUT_ + lane];
  float s = 0.f, ss = 0.f;
  for (int v = wv; v < NV; v += nw) {
    const float* xr = x + (size_t)v * CIN_;
    float d = 0.f;
#pragma unroll
    for (int ci = 0; ci < CIN_; ++ci) d = fmaf(xr[ci], wcol[ci], d);
    s += d;
    ss = fmaf(d, d, ss);
  }
  __shared__ float ls[128];
  if (threadIdx.x < 128) ls[threadIdx.x] = 0.f;
  __syncthreads();
  atomicAdd(&ls[lane], s);
  atomicAdd(&ls[64 + lane], ss);
  __syncthreads();
  if (threadIdx.x < 128) atomicAdd(&sums[threadIdx.x], ls[threadIdx.x]);
}

__global__ void finalize_kernel(const float* __restrict__ sums,
                                const float* __restrict__ g,
                                const float* __restrict__ b,
                                float* __restrict__ out) {
  int c = threadIdx.x;
  float m = sums[c] * (1.0f / NV);
  float var = sums[64 + c] * (1.0f / NV) - m * m;
  float sc = g[c] / sqrtf(var + EPS_);
  out[c] = sc;
  out[64 + c] = b[c] - m * sc;
}

__global__ __launch_bounds__(256) void bnrelu_f16_kernel(
    _Float16* __restrict__ y, const float* __restrict__ scsh) {
  size_t q = (size_t)blockIdx.x * 256 + threadIdx.x;
  if (q >= (size_t)NV * COUT_ / 8) return;
  int c0 = (int)(q & 7) * 8;
  half8 v = ((const half8*)y)[q];
#pragma unroll
  for (int jj = 0; jj < 8; ++jj) {
    float f = fmaxf(fmaf((float)v[jj], scsh[c0 + jj], scsh[64 + c0 + jj]), 0.f);
    v[jj] = (_Float16)f;
  }
  ((half8*)y)[q] = v;
}

__global__ __launch_bounds__(256) void final_kernel(
    const float* __restrict__ x, const float* __restrict__ wid,
    float* __restrict__ y2out, const float* __restrict__ ss2,
    const float* __restrict__ ssid) {
  int lane = threadIdx.x & 63;
  int wv = blockIdx.x * 4 + (threadIdx.x >> 6);
  int nw = gridDim.x * 4;
  float wcol[CIN_];
#pragma unroll
  for (int ci = 0; ci < CIN_; ++ci) wcol[ci] = wid[ci * COUT_ + lane];
  float sc2 = ss2[lane], sh2 = ss2[64 + lane];
  float sci = ssid[lane], shi = ssid[64 + lane];
  for (int v = wv; v < NV; v += nw) {
    const float* xr = x + (size_t)v * CIN_;
    float d = 0.f;
#pragma unroll
    for (int ci = 0; ci < CIN_; ++ci) d = fmaf(xr[ci], wcol[ci], d);
    size_t o = (size_t)v * COUT_ + lane;
    float r = fmaf(y2out[o], sc2, sh2) + fmaf(d, sci, shi);
    y2out[o] = fmaxf(r, 0.f);
  }
}

extern "C" void kernel_launch(void* const* d_in, const int* in_sizes, int n_in,
                              void* d_out, int out_size, void* d_ws, size_t ws_size,
                              hipStream_t stream) {
  const float* x   = (const float*)d_in[0];
  const int*   nbr = (const int*)d_in[1];
  const float* w1  = (const float*)d_in[2];
  const float* g1  = (const float*)d_in[3];
  const float* b1  = (const float*)d_in[4];
  const float* w2  = (const float*)d_in[5];
  const float* g2  = (const float*)d_in[6];
  const float* b2  = (const float*)d_in[7];
  const float* wid = (const float*)d_in[8];
  const float* gid = (const float*)d_in[9];
  const float* bid = (const float*)d_in[10];
  float* out = (float*)d_out;

  _Float16* y1h = (_Float16*)d_ws;
  _Float16* xh  = y1h + (size_t)NV * COUT_;
  _Float16* wT1 = xh + (size_t)NV * CIN_;
  _Float16* wT2 = wT1 + KOFF * COUT_ * CIN_;
  float*    st  = (float*)(wT2 + KOFF * COUT_ * COUT_);

  const int NWG = (NV + 255) / 256;  // 1024 thr = 16 waves x 16 voxels

  zero_stats_kernel<<<1, 384, 0, stream>>>(st);
  cast_x_kernel<<<(NV * CIN_ / 8 + 255) / 256, 256, 0, stream>>>(x, xh);
  wtrans_kernel<<<(KOFF * CIN_ * COUT_ + 255) / 256, 256, 0, stream>>>(w1, wT1, CIN_);
  wtrans_kernel<<<(KOFF * COUT_ * COUT_ + 255) / 256, 256, 0, stream>>>(w2, wT2, COUT_);

  // conv1 with fused BN1 stats -> st[0:128)
  conv_mfma_v8<CIN_, true><<<NWG, 1024, 0, stream>>>(xh, nbr, wT1, nullptr, y1h, st + 0);
  ident_stats_kernel<<<2048, 256, 0, stream>>>(x, wid, st + 256);
  finalize_kernel<<<1, 64, 0, stream>>>(st + 0, g1, b1, st + 384);
  finalize_kernel<<<1, 64, 0, stream>>>(st + 256, gid, bid, st + 640);
  bnrelu_f16_kernel<<<(NV * COUT_ / 8 + 255) / 256, 256, 0, stream>>>(y1h, st + 384);

  // conv2 with fused BN2 stats -> st[128:256)
  conv_mfma_v8<COUT_, false><<<NWG, 1024, 0, stream>>>(y1h, nbr, wT2, out, nullptr, st + 128);
  finalize_kernel<<<1, 64, 0, stream>>>(st + 128, g2, b2, st + 512);
  final_kernel<<<4096, 256, 0, stream>>>(x, wid, out, st + 512, st + 640);
}

// Round 6
// 1059.301 us; speedup vs baseline: 3.0241x; 3.0241x over previous
//
#include <hip/hip_runtime.h>

#define NV 500000
#define KOFF 27
#define CIN_ 32
#define COUT_ 64
#define EPS_ 1e-5f

typedef __attribute__((ext_vector_type(8))) _Float16 half8;
typedef __attribute__((ext_vector_type(4))) float floatx4;

// ws layout: y1h NV*64 f16 | xh NV*32 f16 | wT1 27*64*32 f16 | wT2 27*64*64 f16 | st 384 f32
// st: [0:128) BN1 sums | [128:256) BN2 sums | [256:384) ident sums

__global__ void zero_stats_kernel(float* __restrict__ s) {
  if (threadIdx.x < 384) s[threadIdx.x] = 0.f;
}

// ---- fused prep: cast_x | wtrans1 | wtrans2 | ident_stats, by blockIdx range ----
#define CAST_BLKS ((NV * CIN_ / 8 + 255) / 256)
#define WT1_BLKS ((KOFF * CIN_ * COUT_ + 255) / 256)
#define WT2_BLKS ((KOFF * COUT_ * COUT_ + 255) / 256)
#define IDST_BLKS 2048

__global__ __launch_bounds__(256) void prep_kernel(
    const float* __restrict__ x, _Float16* __restrict__ xh,
    const float* __restrict__ w1, _Float16* __restrict__ wT1,
    const float* __restrict__ w2, _Float16* __restrict__ wT2,
    const float* __restrict__ wid, float* __restrict__ idsums) {
  int b = blockIdx.x;
  if (b < CAST_BLKS) {
    size_t q = (size_t)b * 256 + threadIdx.x;
    if (q >= (size_t)NV * CIN_ / 8) return;
    const float4* xp = (const float4*)x;
    float4 a = xp[2 * q], c = xp[2 * q + 1];
    half8 h;
    h[0] = (_Float16)a.x; h[1] = (_Float16)a.y; h[2] = (_Float16)a.z; h[3] = (_Float16)a.w;
    h[4] = (_Float16)c.x; h[5] = (_Float16)c.y; h[6] = (_Float16)c.z; h[7] = (_Float16)c.w;
    ((half8*)xh)[q] = h;
  } else if (b < CAST_BLKS + WT1_BLKS) {
    int t = (b - CAST_BLKS) * 256 + threadIdx.x;
    if (t >= KOFF * CIN_ * COUT_) return;
    int k = t / (CIN_ * COUT_);
    int r = t % (CIN_ * COUT_);
    int co = r / CIN_;
    int ci = r % CIN_;
    wT1[t] = (_Float16)w1[(k * CIN_ + ci) * COUT_ + co];
  } else if (b < CAST_BLKS + WT1_BLKS + WT2_BLKS) {
    int t = (b - CAST_BLKS - WT1_BLKS) * 256 + threadIdx.x;
    if (t >= KOFF * COUT_ * COUT_) return;
    int k = t / (COUT_ * COUT_);
    int r = t % (COUT_ * COUT_);
    int co = r / COUT_;
    int ci = r % COUT_;
    wT2[t] = (_Float16)w2[(k * COUT_ + ci) * COUT_ + co];
  } else {
    int bb = b - CAST_BLKS - WT1_BLKS - WT2_BLKS;
    int lane = threadIdx.x & 63;
    int wv = bb * 4 + (threadIdx.x >> 6);
    int nw = IDST_BLKS * 4;
    float wcol[CIN_];
#pragma unroll
    for (int ci = 0; ci < CIN_; ++ci) wcol[ci] = wid[ci * COUT_ + lane];
    float s = 0.f, ss = 0.f;
    for (int v = wv; v < NV; v += nw) {
      const float* xr = x + (size_t)v * CIN_;
      float d = 0.f;
#pragma unroll
      for (int ci = 0; ci < CIN_; ++ci) d = fmaf(xr[ci], wcol[ci], d);
      s += d;
      ss = fmaf(d, d, ss);
    }
    __shared__ float ls[128];
    if (threadIdx.x < 128) ls[threadIdx.x] = 0.f;
    __syncthreads();
    atomicAdd(&ls[lane], s);
    atomicAdd(&ls[64 + lane], ss);
    __syncthreads();
    if (threadIdx.x < 128) atomicAdd(&idsums[threadIdx.x], ls[threadIdx.x]);
  }
}

// ---- conv v9: EXACT v3 main loop (proven 300us, VGPR 48, spill-free) ----
// + fused BN stats epilogue (proven in v6/v8). Structure: 1024 thr, 16 waves,
// 32 voxels/wave (2 groups), D=3/4 ring, (1024,4) launch bounds.

template<int CI>
__device__ __forceinline__ void stageB(const _Float16* __restrict__ wT,
                                       _Float16* __restrict__ lds,
                                       int k0, int kp, int tid) {
  __syncthreads();  // all waves done reading previous phase's LDS
  const int segs = CI / 8;
  const int chunks = kp * COUT_ * segs;
  for (int idx = tid; idx < chunks; idx += 1024) {
    int row = idx / segs;
    int s = idx - row * segs;
    half8 v = *(const half8*)(wT + ((size_t)k0 * COUT_ + row) * CI + s * 8);
    *(half8*)(lds + (size_t)row * (CI + 8) + s * 8) = v;
  }
  __syncthreads();
}

template<int CI, int KPC, int D>
__device__ __forceinline__ void run_phase(
    const half8* __restrict__ fp, const int* __restrict__ nbr,
    const _Float16* __restrict__ lds, int k0,
    int v0, int v1, int m, int quad, floatx4 acc[2][4]) {
  constexpr int SEG = CI / 32;
  constexpr int ROWH8 = CI / 8;

  // preload ALL phase indices first: later address consumption never waits
  // on a recently-issued load (vmcnt drains in order)
  int j0[KPC], j1[KPC];
#pragma unroll
  for (int k = 0; k < KPC; ++k) {
    j0[k] = nbr[(k0 + k) * NV + v0] * ROWH8;
    j1[k] = nbr[(k0 + k) * NV + v1] * ROWH8;
  }

  half8 ring[D][2][SEG];
#pragma unroll
  for (int p = 0; p < D; ++p) {
#pragma unroll
    for (int s = 0; s < SEG; ++s) {
      ring[p][0][s] = fp[(size_t)j0[p] + s * 4 + quad];
      ring[p][1][s] = fp[(size_t)j1[p] + s * 4 + quad];
    }
  }

#pragma unroll
  for (int k = 0; k < KPC; ++k) {
    const _Float16* bk = lds + (size_t)k * COUT_ * (CI + 8);
#pragma unroll
    for (int s = 0; s < SEG; ++s) {
#pragma unroll
      for (int nf = 0; nf < 4; ++nf) {
        half8 bf = *(const half8*)(bk + (nf * 16 + m) * (CI + 8) + s * 32 + quad * 8);
        acc[0][nf] = __builtin_amdgcn_mfma_f32_16x16x32_f16(ring[k % D][0][s], bf, acc[0][nf], 0, 0, 0);
        acc[1][nf] = __builtin_amdgcn_mfma_f32_16x16x32_f16(ring[k % D][1][s], bf, acc[1][nf], 0, 0, 0);
      }
    }
    if (k + D < KPC) {
#pragma unroll
      for (int s = 0; s < SEG; ++s) {
        ring[k % D][0][s] = fp[(size_t)j0[k + D] + s * 4 + quad];
        ring[k % D][1][s] = fp[(size_t)j1[k + D] + s * 4 + quad];
      }
    }
  }
}

template<int CI, bool WF16>
__global__ __launch_bounds__(1024, 4) void conv_mfma_v9(
    const _Float16* __restrict__ feats, const int* __restrict__ nbr,
    const _Float16* __restrict__ wT, float* __restrict__ outF,
    _Float16* __restrict__ outH, float* __restrict__ stOut) {
  constexpr int LDSH = (CI == 64) ? 7 * 64 * 72 : 9 * 64 * 40;
  __shared__ __align__(16) _Float16 ldsB[LDSH];
  __shared__ float bs[128];  // block-level stats reduce (sum | sumsq)

  int tid = threadIdx.x;
  int wave = tid >> 6, lane = tid & 63;
  int m = lane & 15, quad = lane >> 4;
  int vbase = (blockIdx.x * 16 + wave) * 32;  // 32 voxels per wave
  int v0 = vbase + m;
  int v1 = vbase + 16 + m;
  v0 = v0 < NV ? v0 : NV - 1;
  v1 = v1 < NV ? v1 : NV - 1;
  const half8* fp = (const half8*)feats;

  if (tid < 128) bs[tid] = 0.f;  // ordered by stageB's first __syncthreads

  floatx4 acc[2][4];
#pragma unroll
  for (int g = 0; g < 2; ++g)
#pragma unroll
    for (int nf = 0; nf < 4; ++nf) acc[g][nf] = (floatx4){0.f, 0.f, 0.f, 0.f};

  if constexpr (CI == 64) {
    stageB<CI>(wT, ldsB, 0, 7, tid);
    run_phase<CI, 7, 3>(fp, nbr, ldsB, 0, v0, v1, m, quad, acc);
    stageB<CI>(wT, ldsB, 7, 7, tid);
    run_phase<CI, 7, 3>(fp, nbr, ldsB, 7, v0, v1, m, quad, acc);
    stageB<CI>(wT, ldsB, 14, 7, tid);
    run_phase<CI, 7, 3>(fp, nbr, ldsB, 14, v0, v1, m, quad, acc);
    stageB<CI>(wT, ldsB, 21, 6, tid);
    run_phase<CI, 6, 3>(fp, nbr, ldsB, 21, v0, v1, m, quad, acc);
  } else {
    stageB<CI>(wT, ldsB, 0, 9, tid);
    run_phase<CI, 9, 4>(fp, nbr, ldsB, 0, v0, v1, m, quad, acc);
    stageB<CI>(wT, ldsB, 9, 9, tid);
    run_phase<CI, 9, 4>(fp, nbr, ldsB, 9, v0, v1, m, quad, acc);
    stageB<CI>(wT, ldsB, 18, 9, tid);
    run_phase<CI, 9, 4>(fp, nbr, ldsB, 18, v0, v1, m, quad, acc);
  }

  // epilogue: store + fused BN stats (sum / sumsq per channel)
  float s4[4], q4[4];
#pragma unroll
  for (int nf = 0; nf < 4; ++nf) { s4[nf] = 0.f; q4[nf] = 0.f; }
#pragma unroll
  for (int g = 0; g < 2; ++g)
#pragma unroll
    for (int nf = 0; nf < 4; ++nf)
#pragma unroll
      for (int r = 0; r < 4; ++r) {
        int row = vbase + g * 16 + quad * 4 + r;
        if (row < NV) {
          float v = acc[g][nf][r];
          size_t o = (size_t)row * COUT_ + nf * 16 + m;
          if (WF16) outH[o] = (_Float16)v;
          else outF[o] = v;
          s4[nf] += v;
          q4[nf] = fmaf(v, v, q4[nf]);
        }
      }
  // reduce over the 4 quads: lanes m, m+16, m+32, m+48 hold channel nf*16+m
#pragma unroll
  for (int nf = 0; nf < 4; ++nf) {
    s4[nf] += __shfl_xor(s4[nf], 16); s4[nf] += __shfl_xor(s4[nf], 32);
    q4[nf] += __shfl_xor(q4[nf], 16); q4[nf] += __shfl_xor(q4[nf], 32);
  }
  if (quad == 0) {
#pragma unroll
    for (int nf = 0; nf < 4; ++nf) {
      atomicAdd(&bs[nf * 16 + m], s4[nf]);
      atomicAdd(&bs[64 + nf * 16 + m], q4[nf]);
    }
  }
  __syncthreads();
  if (tid < 128) atomicAdd(&stOut[tid], bs[tid]);
}

// ---- BN1 apply (inline finalize from sums) ----

__global__ __launch_bounds__(256) void bnrelu_f16_kernel(
    _Float16* __restrict__ y, const float* __restrict__ sums,
    const float* __restrict__ g, const float* __restrict__ b) {
  __shared__ float scsh[128];
  if (threadIdx.x < 64) {
    int c = threadIdx.x;
    float mm = sums[c] * (1.0f / NV);
    float var = sums[64 + c] * (1.0f / NV) - mm * mm;
    float sc = g[c] / sqrtf(var + EPS_);
    scsh[c] = sc;
    scsh[64 + c] = b[c] - mm * sc;
  }
  __syncthreads();
  size_t q = (size_t)blockIdx.x * 256 + threadIdx.x;
  if (q >= (size_t)NV * COUT_ / 8) return;
  int c0 = (int)(q & 7) * 8;
  half8 v = ((const half8*)y)[q];
#pragma unroll
  for (int jj = 0; jj < 8; ++jj) {
    float f = fmaxf(fmaf((float)v[jj], scsh[c0 + jj], scsh[64 + c0 + jj]), 0.f);
    v[jj] = (_Float16)f;
  }
  ((half8*)y)[q] = v;
}

// ---- final: BN2 + BN(ident) + add + ReLU, coefficients from sums ----

__global__ __launch_bounds__(256) void final_kernel(
    const float* __restrict__ x, const float* __restrict__ wid,
    float* __restrict__ y2out, const float* __restrict__ sums2,
    const float* __restrict__ sumsid,
    const float* __restrict__ g2, const float* __restrict__ b2,
    const float* __restrict__ gid, const float* __restrict__ bid) {
  int lane = threadIdx.x & 63;
  int wv = blockIdx.x * 4 + (threadIdx.x >> 6);
  int nw = gridDim.x * 4;
  float wcol[CIN_];
#pragma unroll
  for (int ci = 0; ci < CIN_; ++ci) wcol[ci] = wid[ci * COUT_ + lane];
  float m2 = sums2[lane] * (1.0f / NV);
  float var2 = sums2[64 + lane] * (1.0f / NV) - m2 * m2;
  float sc2 = g2[lane] / sqrtf(var2 + EPS_);
  float sh2 = b2[lane] - m2 * sc2;
  float mi = sumsid[lane] * (1.0f / NV);
  float vari = sumsid[64 + lane] * (1.0f / NV) - mi * mi;
  float sci = gid[lane] / sqrtf(vari + EPS_);
  float shi = bid[lane] - mi * sci;
  for (int v = wv; v < NV; v += nw) {
    const float* xr = x + (size_t)v * CIN_;
    float d = 0.f;
#pragma unroll
    for (int ci = 0; ci < CIN_; ++ci) d = fmaf(xr[ci], wcol[ci], d);
    size_t o = (size_t)v * COUT_ + lane;
    float r = fmaf(y2out[o], sc2, sh2) + fmaf(d, sci, shi);
    y2out[o] = fmaxf(r, 0.f);
  }
}

extern "C" void kernel_launch(void* const* d_in, const int* in_sizes, int n_in,
                              void* d_out, int out_size, void* d_ws, size_t ws_size,
                              hipStream_t stream) {
  const float* x   = (const float*)d_in[0];
  const int*   nbr = (const int*)d_in[1];
  const float* w1  = (const float*)d_in[2];
  const float* g1  = (const float*)d_in[3];
  const float* b1  = (const float*)d_in[4];
  const float* w2  = (const float*)d_in[5];
  const float* g2  = (const float*)d_in[6];
  const float* b2  = (const float*)d_in[7];
  const float* wid = (const float*)d_in[8];
  const float* gid = (const float*)d_in[9];
  const float* bid = (const float*)d_in[10];
  float* out = (float*)d_out;

  _Float16* y1h = (_Float16*)d_ws;
  _Float16* xh  = y1h + (size_t)NV * COUT_;
  _Float16* wT1 = xh + (size_t)NV * CIN_;
  _Float16* wT2 = wT1 + KOFF * COUT_ * CIN_;
  float*    st  = (float*)(wT2 + KOFF * COUT_ * COUT_);

  const int NWG = (NV + 511) / 512;  // 1024 thr = 16 waves x 32 voxels
  const int PREP_BLKS = CAST_BLKS + WT1_BLKS + WT2_BLKS + IDST_BLKS;

  zero_stats_kernel<<<1, 384, 0, stream>>>(st);
  prep_kernel<<<PREP_BLKS, 256, 0, stream>>>(x, xh, w1, wT1, w2, wT2, wid, st + 256);

  // conv1 with fused BN1 stats -> st[0:128)
  conv_mfma_v9<CIN_, true><<<NWG, 1024, 0, stream>>>(xh, nbr, wT1, nullptr, y1h, st + 0);
  bnrelu_f16_kernel<<<(NV * COUT_ / 8 + 255) / 256, 256, 0, stream>>>(y1h, st + 0, g1, b1);

  // conv2 with fused BN2 stats -> st[128:256)
  conv_mfma_v9<COUT_, false><<<NWG, 1024, 0, stream>>>(y1h, nbr, wT2, out, nullptr, st + 128);
  final_kernel<<<4096, 256, 0, stream>>>(x, wid, out, st + 128, st + 256,
                                         g2, b2, gid, bid);
}